// Round 4
// baseline (294.078 us; speedup 1.0000x reference)
//
#include <hip/hip_runtime.h>
#include <math.h>

// Problem: B=64, N=4096, K=128. Labels C in [0,128).
// out[b,i,k] = (rank(C[b,i]) == k) ? u : ndtri(clip(U,1e-7,1-1e-7) * Phi(u))
// where u = mu + sigma*eps[b,i], rank = index of C[b,i] in sorted unique(C).
//
// Structure (v4):
//   ws[0..3] : 128-bit presence bitmap over label values (zeroed via tiny memset)
// Pass 1 (bitmap_kernel): presence bitmap only — reads just C (1 MiB, ~2 us)
// Pass 2 (map_kernel): THREAD-COARSENED 4x — each thread owns 4 consecutive
//   float4s (64 B) of ONE row. erfcf redundancy drops 32x->8x per row; rank
//   popcount and addressing amortized 4x. Loads are dwordx4 at 64-B lane
//   stride (each 64-B line fully consumed by its thread; L1 serves the rest).
//   Branchless Acklam ndtri, single rcp, nontemporal stores.

// Native clang vector type — __builtin_nontemporal_store rejects
// HIP_vector_type<float,4> but accepts ext_vector_type.
typedef float vfloat4 __attribute__((ext_vector_type(4)));

// ---------------------------------------------------------------------------
// Acklam's inverse normal CDF, fp32, branchless. Both rational paths are
// evaluated (every wave is divergent anyway: tail probability ~11%/element),
// then num/den/scale are selected and ONE rcp is paid instead of two.
// Per-lane arithmetic is bit-identical to the branched version.
__device__ __forceinline__ float ndtri_fast(float p) {
    const float omp  = 1.0f - p;
    const bool upper = p > 0.5f;
    const float pm   = upper ? omp : p;   // min(p, 1-p)
    const bool tail  = pm < 0.02425f;

    // ---- tail branch values (valid/finite for all lanes: pm in (0, 0.5])
    float qt = sqrtf(-2.0f * __logf(pm));
    float numT = -0.007784894002430293f;
    numT = fmaf(numT, qt, -0.3223964580411365f);
    numT = fmaf(numT, qt, -2.400758277161838f);
    numT = fmaf(numT, qt, -2.549732539343734f);
    numT = fmaf(numT, qt,  4.374664141464968f);
    numT = fmaf(numT, qt,  2.938163982698783f);
    float denT = 0.007784695709041462f;
    denT = fmaf(denT, qt, 0.3224671290700398f);
    denT = fmaf(denT, qt, 2.445134137142996f);
    denT = fmaf(denT, qt, 3.754408661907416f);
    denT = fmaf(denT, qt, 1.0f);

    // ---- central branch values
    float qc = p - 0.5f;
    float r  = qc * qc;
    float numC = -39.69683028665376f;
    numC = fmaf(numC, r,  220.9460984245205f);
    numC = fmaf(numC, r, -275.9285104469687f);
    numC = fmaf(numC, r,  138.3577518672690f);
    numC = fmaf(numC, r,  -30.66479806614716f);
    numC = fmaf(numC, r,    2.506628277459239f);
    float denC = -54.47609879822406f;
    denC = fmaf(denC, r,  161.5858368580409f);
    denC = fmaf(denC, r, -155.6989798598866f);
    denC = fmaf(denC, r,   66.80131188771972f);
    denC = fmaf(denC, r,  -13.28068155288572f);
    denC = fmaf(denC, r,    1.0f);

    // ---- select + single rcp
    float num = tail ? numT : numC;
    float den = tail ? denT : denC;
    float s   = tail ? (upper ? -1.0f : 1.0f) : qc;
    return s * num * __builtin_amdgcn_rcpf(den);
}

__device__ __forceinline__ void set_label_bit(int c, unsigned& m0, unsigned& m1,
                                              unsigned& m2, unsigned& m3) {
    unsigned bit = 1u << (c & 31);
    int w = (c >> 5) & 3;
    if      (w == 0) m0 |= bit;
    else if (w == 1) m1 |= bit;
    else if (w == 2) m2 |= bit;
    else             m3 |= bit;
}

// ---------------------------------------------------------------------------
// Pass 1: presence bitmap only. 4 labels per thread (int4 loads).
__global__ void __launch_bounds__(256) bitmap_kernel(
    const int* __restrict__ C,
    unsigned* __restrict__ mask,
    int n)
{
    __shared__ unsigned sm[4];
    if (threadIdx.x < 4) sm[threadIdx.x] = 0u;
    __syncthreads();

    int i = blockIdx.x * blockDim.x + threadIdx.x;
    int base = i << 2;
    unsigned m0 = 0, m1 = 0, m2 = 0, m3 = 0;

    if (base + 3 < n) {
        int4 c = *reinterpret_cast<const int4*>(C + base);
        set_label_bit(c.x, m0, m1, m2, m3);
        set_label_bit(c.y, m0, m1, m2, m3);
        set_label_bit(c.z, m0, m1, m2, m3);
        set_label_bit(c.w, m0, m1, m2, m3);
    } else {
        for (int j = base; j < n && j < base + 4; ++j)
            set_label_bit(C[j], m0, m1, m2, m3);
    }

    #pragma unroll
    for (int off = 32; off > 0; off >>= 1) {
        m0 |= __shfl_down(m0, off, 64);
        m1 |= __shfl_down(m1, off, 64);
        m2 |= __shfl_down(m2, off, 64);
        m3 |= __shfl_down(m3, off, 64);
    }
    if ((threadIdx.x & 63) == 0) {
        if (m0) atomicOr(&sm[0], m0);
        if (m1) atomicOr(&sm[1], m1);
        if (m2) atomicOr(&sm[2], m2);
        if (m3) atomicOr(&sm[3], m3);
    }
    __syncthreads();
    if (threadIdx.x < 4) {
        unsigned v = sm[threadIdx.x];
        if (v) atomicOr(&mask[threadIdx.x], v);
    }
}

// ---------------------------------------------------------------------------
// Process one float4 of U into one output float4 (bit-identical math).
__device__ __forceinline__ vfloat4 do_quad(float4 Uv, float phi, float u,
                                           int rank, int kbase) {
    const float lo = 1e-7f;
    const float hi = 0.99999988079071045f;  // fp32(1 - 1e-7), matches jnp.clip
    float p0 = __builtin_amdgcn_fmed3f(Uv.x, lo, hi) * phi;
    float p1 = __builtin_amdgcn_fmed3f(Uv.y, lo, hi) * phi;
    float p2 = __builtin_amdgcn_fmed3f(Uv.z, lo, hi) * phi;
    float p3 = __builtin_amdgcn_fmed3f(Uv.w, lo, hi) * phi;
    float z0 = ndtri_fast(p0);
    float z1 = ndtri_fast(p1);
    float z2 = ndtri_fast(p2);
    float z3 = ndtri_fast(p3);
    vfloat4 o;
    o.x = (kbase + 0 == rank) ? u : z0;
    o.y = (kbase + 1 == rank) ? u : z1;
    o.z = (kbase + 2 == rank) ? u : z2;
    o.w = (kbase + 3 == rank) ? u : z3;
    return o;
}

__device__ __forceinline__ int rank_of(int c, uint4 w) {
    int cw = c >> 5;
    unsigned below = (1u << (c & 31)) - 1u;
    return __popc(w.x & ((0 < cw) ? 0xFFFFFFFFu : ((0 == cw) ? below : 0u)))
         + __popc(w.y & ((1 < cw) ? 0xFFFFFFFFu : ((1 == cw) ? below : 0u)))
         + __popc(w.z & ((2 < cw) ? 0xFFFFFFFFu : ((2 == cw) ? below : 0u)))
         + __popc(w.w & ((3 < cw) ? 0xFFFFFFFFu : ((3 == cw) ? below : 0u)));
}

// ---------------------------------------------------------------------------
// Pass 2: one thread per 4 float4s (16 consecutive k of one row).
__global__ void __launch_bounds__(256) map_kernel(
    const int* __restrict__ C,
    const float* __restrict__ eps,
    const float* __restrict__ mu_p,
    const float* __restrict__ sigma_p,
    const float4* __restrict__ U4,
    const uint4* __restrict__ mask4,
    float4* __restrict__ out4,
    int total4)
{
    int tid = blockIdx.x * blockDim.x + threadIdx.x;
    int base4 = tid << 2;                 // first float4 index of this thread

    const float sg = sigma_p[0];          // uniform -> scalar load
    const float mu = mu_p[0];
    uint4 w = *mask4;                     // same 16B for all threads -> broadcast

    if (base4 + 3 < total4) {
        int row = tid >> 3;               // 8 threads per row (32 float4/row)
        int k0  = (tid & 7) << 4;         // 16 k-values per thread

        // issue all 4 vector loads up front
        float4 v0 = U4[base4 + 0];
        float4 v1 = U4[base4 + 1];
        float4 v2 = U4[base4 + 2];
        float4 v3 = U4[base4 + 3];
        float  e  = eps[row];             // 8 threads share -> L1 broadcast
        int    c  = C[row];

        float u   = fmaf(sg, e, mu);
        float phi = 0.5f * erfcf(-u * 0.7071067811865476f);
        int rank  = rank_of(c, w);

        vfloat4 o0 = do_quad(v0, phi, u, rank, k0 + 0);
        vfloat4 o1 = do_quad(v1, phi, u, rank, k0 + 4);
        vfloat4 o2 = do_quad(v2, phi, u, rank, k0 + 8);
        vfloat4 o3 = do_quad(v3, phi, u, rank, k0 + 12);

        // out is never re-read: stream it past the caches
        vfloat4* op = reinterpret_cast<vfloat4*>(&out4[base4]);
        __builtin_nontemporal_store(o0, op + 0);
        __builtin_nontemporal_store(o1, op + 1);
        __builtin_nontemporal_store(o2, op + 2);
        __builtin_nontemporal_store(o3, op + 3);
    } else if (base4 < total4) {
        // tail (not hit for this shape: total4 % 4 == 0), per-float4 fallback
        for (int idx = base4; idx < total4; ++idx) {
            int row = idx >> 5;
            int k0  = (idx & 31) << 2;
            float4 Uv = U4[idx];
            float  e  = eps[row];
            int    c  = C[row];
            float u   = fmaf(sg, e, mu);
            float phi = 0.5f * erfcf(-u * 0.7071067811865476f);
            int rank  = rank_of(c, w);
            vfloat4 o = do_quad(Uv, phi, u, rank, k0);
            __builtin_nontemporal_store(o, reinterpret_cast<vfloat4*>(&out4[idx]));
        }
    }
}

extern "C" void kernel_launch(void* const* d_in, const int* in_sizes, int n_in,
                              void* d_out, int out_size, void* d_ws, size_t ws_size,
                              hipStream_t stream) {
    const int*   C     = (const int*)d_in[0];
    const float* eps   = (const float*)d_in[1];
    const float4* U4   = (const float4*)d_in[2];
    const float* mu    = (const float*)d_in[3];
    const float* sigma = (const float*)d_in[4];
    float4* out4 = (float4*)d_out;

    unsigned* mask = (unsigned*)d_ws;

    int n = in_sizes[0];           // B*N = 262144 rows
    int total4 = out_size / 4;     // float4 count (unchanged from verified baseline)

    // ws is re-poisoned to 0xAA before every timed launch — zero the bitmap.
    (void)hipMemsetAsync(d_ws, 0, 4 * sizeof(unsigned), stream);

    int n4 = (n + 3) >> 2;
    int bb = (n4 + 255) / 256;
    bitmap_kernel<<<bb, 256, 0, stream>>>(C, mask, n);

    int nthreads = (total4 + 3) >> 2;              // 4 float4 per thread
    int mb = (nthreads + 255) / 256;
    map_kernel<<<mb, 256, 0, stream>>>(C, eps, mu, sigma, U4,
                                       (const uint4*)mask, out4, total4);
}

// Round 5
// 250.700 us; speedup vs baseline: 1.1730x; 1.1730x over previous
//
#include <hip/hip_runtime.h>
#include <math.h>

// Problem: B=64, N=4096, K=128. Labels C in [0,128).
// out[b,i,k] = (rank(C[b,i]) == k) ? u : ndtri(clip(U,1e-7,1-1e-7) * Phi(u))
// where u = mu + sigma*eps[b,i], rank = index of C[b,i] in sorted unique(C).
//
// Structure (v5 = verified v3 layout + nontemporal U loads):
//   ws[0..3] : 128-bit presence bitmap over label values (zeroed via tiny memset)
// Pass 1 (bitmap_kernel): presence bitmap only — reads just C (1 MiB, ~2 us)
// Pass 2 (map_kernel): ONE float4 per thread (fully coalesced — R4's 4x
//   coarsening with 64-B lane stride broke coalescing: 29% HBM, 1.6x write
//   amplification). u/Phi(u) recomputed per thread (bit-identical, hidden
//   under HBM traffic). Branchless Acklam ndtri, single rcp. U is loaded
//   nontemporally (read-once) and out stored nontemporally (write-once).

// Native clang vector type — __builtin_nontemporal_* rejects
// HIP_vector_type<float,4> but accepts ext_vector_type.
typedef float vfloat4 __attribute__((ext_vector_type(4)));

// ---------------------------------------------------------------------------
// Acklam's inverse normal CDF, fp32, branchless. Both rational paths are
// evaluated (every wave is divergent anyway: tail probability ~11%/element),
// then num/den/scale are selected and ONE rcp is paid instead of two.
// Per-lane arithmetic is bit-identical to the branched version.
__device__ __forceinline__ float ndtri_fast(float p) {
    const float omp  = 1.0f - p;
    const bool upper = p > 0.5f;
    const float pm   = upper ? omp : p;   // min(p, 1-p)
    const bool tail  = pm < 0.02425f;

    // ---- tail branch values (valid/finite for all lanes: pm in (0, 0.5])
    float qt = sqrtf(-2.0f * __logf(pm));
    float numT = -0.007784894002430293f;
    numT = fmaf(numT, qt, -0.3223964580411365f);
    numT = fmaf(numT, qt, -2.400758277161838f);
    numT = fmaf(numT, qt, -2.549732539343734f);
    numT = fmaf(numT, qt,  4.374664141464968f);
    numT = fmaf(numT, qt,  2.938163982698783f);
    float denT = 0.007784695709041462f;
    denT = fmaf(denT, qt, 0.3224671290700398f);
    denT = fmaf(denT, qt, 2.445134137142996f);
    denT = fmaf(denT, qt, 3.754408661907416f);
    denT = fmaf(denT, qt, 1.0f);

    // ---- central branch values
    float qc = p - 0.5f;
    float r  = qc * qc;
    float numC = -39.69683028665376f;
    numC = fmaf(numC, r,  220.9460984245205f);
    numC = fmaf(numC, r, -275.9285104469687f);
    numC = fmaf(numC, r,  138.3577518672690f);
    numC = fmaf(numC, r,  -30.66479806614716f);
    numC = fmaf(numC, r,    2.506628277459239f);
    float denC = -54.47609879822406f;
    denC = fmaf(denC, r,  161.5858368580409f);
    denC = fmaf(denC, r, -155.6989798598866f);
    denC = fmaf(denC, r,   66.80131188771972f);
    denC = fmaf(denC, r,  -13.28068155288572f);
    denC = fmaf(denC, r,    1.0f);

    // ---- select + single rcp
    float num = tail ? numT : numC;
    float den = tail ? denT : denC;
    float s   = tail ? (upper ? -1.0f : 1.0f) : qc;
    return s * num * __builtin_amdgcn_rcpf(den);
}

__device__ __forceinline__ void set_label_bit(int c, unsigned& m0, unsigned& m1,
                                              unsigned& m2, unsigned& m3) {
    unsigned bit = 1u << (c & 31);
    int w = (c >> 5) & 3;
    if      (w == 0) m0 |= bit;
    else if (w == 1) m1 |= bit;
    else if (w == 2) m2 |= bit;
    else             m3 |= bit;
}

// ---------------------------------------------------------------------------
// Pass 1: presence bitmap only. 4 labels per thread (int4 loads).
__global__ void __launch_bounds__(256) bitmap_kernel(
    const int* __restrict__ C,
    unsigned* __restrict__ mask,
    int n)
{
    __shared__ unsigned sm[4];
    if (threadIdx.x < 4) sm[threadIdx.x] = 0u;
    __syncthreads();

    int i = blockIdx.x * blockDim.x + threadIdx.x;
    int base = i << 2;
    unsigned m0 = 0, m1 = 0, m2 = 0, m3 = 0;

    if (base + 3 < n) {
        int4 c = *reinterpret_cast<const int4*>(C + base);
        set_label_bit(c.x, m0, m1, m2, m3);
        set_label_bit(c.y, m0, m1, m2, m3);
        set_label_bit(c.z, m0, m1, m2, m3);
        set_label_bit(c.w, m0, m1, m2, m3);
    } else {
        for (int j = base; j < n && j < base + 4; ++j)
            set_label_bit(C[j], m0, m1, m2, m3);
    }

    #pragma unroll
    for (int off = 32; off > 0; off >>= 1) {
        m0 |= __shfl_down(m0, off, 64);
        m1 |= __shfl_down(m1, off, 64);
        m2 |= __shfl_down(m2, off, 64);
        m3 |= __shfl_down(m3, off, 64);
    }
    if ((threadIdx.x & 63) == 0) {
        if (m0) atomicOr(&sm[0], m0);
        if (m1) atomicOr(&sm[1], m1);
        if (m2) atomicOr(&sm[2], m2);
        if (m3) atomicOr(&sm[3], m3);
    }
    __syncthreads();
    if (threadIdx.x < 4) {
        unsigned v = sm[threadIdx.x];
        if (v) atomicOr(&mask[threadIdx.x], v);
    }
}

// ---------------------------------------------------------------------------
// Pass 2: one thread per float4 (4 consecutive k of one row).
// u and Phi(u) recomputed here (bit-identical); the 32x redundancy per row
// is pure VALU hidden under HBM traffic (verified R3: removing the uphi
// table pass was neutral-to-positive).
__global__ void __launch_bounds__(256) map_kernel(
    const int* __restrict__ C,
    const float* __restrict__ eps,
    const float* __restrict__ mu_p,
    const float* __restrict__ sigma_p,
    const float4* __restrict__ U4,
    const uint4* __restrict__ mask4,
    float4* __restrict__ out4,
    int total4)
{
    int idx = blockIdx.x * blockDim.x + threadIdx.x;
    if (idx >= total4) return;
    int row = idx >> 5;        // K/4 = 32 float4 per row
    int k0  = (idx & 31) << 2;

    // U is read exactly once -> nontemporal (don't pollute L2/LLC)
    vfloat4 Uv = __builtin_nontemporal_load(
        reinterpret_cast<const vfloat4*>(&U4[idx]));
    float  e  = eps[row];      // 32 threads share each value -> L1 broadcast
    int    c  = C[row];
    uint4  w  = *mask4;        // same 16B for all threads -> broadcast

    const float sg = sigma_p[0];   // uniform address -> scalar load
    const float mu = mu_p[0];
    float u   = fmaf(sg, e, mu);
    float phi = 0.5f * erfcf(-u * 0.7071067811865476f);

    // rank = popcount of presence bits strictly below c
    int cw = c >> 5;
    unsigned below = (1u << (c & 31)) - 1u;
    int rank = __popc(w.x & ((0 < cw) ? 0xFFFFFFFFu : ((0 == cw) ? below : 0u)))
             + __popc(w.y & ((1 < cw) ? 0xFFFFFFFFu : ((1 == cw) ? below : 0u)))
             + __popc(w.z & ((2 < cw) ? 0xFFFFFFFFu : ((2 == cw) ? below : 0u)))
             + __popc(w.w & ((3 < cw) ? 0xFFFFFFFFu : ((3 == cw) ? below : 0u)));

    const float lo = 1e-7f;
    const float hi = 0.99999988079071045f;  // fp32(1 - 1e-7), matches jnp.clip

    // clamp via v_med3_f32 (single instruction)
    float p0 = __builtin_amdgcn_fmed3f(Uv.x, lo, hi) * phi;
    float p1 = __builtin_amdgcn_fmed3f(Uv.y, lo, hi) * phi;
    float p2 = __builtin_amdgcn_fmed3f(Uv.z, lo, hi) * phi;
    float p3 = __builtin_amdgcn_fmed3f(Uv.w, lo, hi) * phi;

    float z0 = ndtri_fast(p0);
    float z1 = ndtri_fast(p1);
    float z2 = ndtri_fast(p2);
    float z3 = ndtri_fast(p3);

    vfloat4 o;
    o.x = (k0 + 0 == rank) ? u : z0;
    o.y = (k0 + 1 == rank) ? u : z1;
    o.z = (k0 + 2 == rank) ? u : z2;
    o.w = (k0 + 3 == rank) ? u : z3;

    // out is never re-read: stream it past the caches (full-line coalesced)
    __builtin_nontemporal_store(o, reinterpret_cast<vfloat4*>(&out4[idx]));
}

extern "C" void kernel_launch(void* const* d_in, const int* in_sizes, int n_in,
                              void* d_out, int out_size, void* d_ws, size_t ws_size,
                              hipStream_t stream) {
    const int*   C     = (const int*)d_in[0];
    const float* eps   = (const float*)d_in[1];
    const float4* U4   = (const float4*)d_in[2];
    const float* mu    = (const float*)d_in[3];
    const float* sigma = (const float*)d_in[4];
    float4* out4 = (float4*)d_out;

    unsigned* mask = (unsigned*)d_ws;

    int n = in_sizes[0];           // B*N = 262144 rows
    int total4 = out_size / 4;     // float4 count (unchanged from verified baseline)

    // ws is re-poisoned to 0xAA before every timed launch — zero the bitmap.
    (void)hipMemsetAsync(d_ws, 0, 4 * sizeof(unsigned), stream);

    int n4 = (n + 3) >> 2;
    int bb = (n4 + 255) / 256;
    bitmap_kernel<<<bb, 256, 0, stream>>>(C, mask, n);

    int mb = (total4 + 255) / 256;
    map_kernel<<<mb, 256, 0, stream>>>(C, eps, mu, sigma, U4,
                                       (const uint4*)mask, out4, total4);
}

// Round 6
// 244.570 us; speedup vs baseline: 1.2024x; 1.0251x over previous
//
#include <hip/hip_runtime.h>
#include <math.h>

// Problem: B=64, N=4096, K=128. Labels C in [0,128).
// out[b,i,k] = (rank(C[b,i]) == k) ? u : ndtri(clip(U,1e-7,1-1e-7) * Phi(u))
// where u = mu + sigma*eps[b,i], rank = index of C[b,i] in sorted unique(C).
//
// Structure (v6 = verified v3 layout + packed-f32 Acklam polys):
//   ws[0..3] : 128-bit presence bitmap over label values (zeroed via tiny memset)
// Pass 1 (bitmap_kernel): presence bitmap only — reads just C (1 MiB, ~2 us)
// Pass 2 (map_kernel): ONE float4 per thread (fully coalesced; R4 showed 4x
//   coarsening at 64-B lane stride breaks coalescing: 29% HBM, 1.6x write amp.
//   R5 showed nontemporal U LOADS cost ~9 us — plain loads here; NT store ok).
//   The Acklam rational polys are evaluated pairwise on float2 via
//   __builtin_elementwise_fma -> v_pk_fma_f32 (44 -> 22 poly insts/thread),
//   elementwise IEEE-identical so absmax is unchanged.

typedef float  vfloat4 __attribute__((ext_vector_type(4)));
typedef float  vfloat2 __attribute__((ext_vector_type(2)));

// ---------------------------------------------------------------------------
// Packed Acklam ndtri for TWO independent p values. Both rational paths are
// evaluated (per-element tail prob ~11% -> every wave diverges anyway); the
// poly chains run on float2 (v_pk_fma_f32), transcendentals stay scalar.
// Per-element arithmetic is bit-identical to the scalar branched version.
__device__ __forceinline__ vfloat2 ndtri2_fast(float pa, float pb) {
    // scalar prep per element
    const bool upA = pa > 0.5f, upB = pb > 0.5f;
    const float pmA = upA ? (1.0f - pa) : pa;
    const float pmB = upB ? (1.0f - pb) : pb;
    const bool tailA = pmA < 0.02425f, tailB = pmB < 0.02425f;

    // tail arg: q = sqrt(-2 ln pm)   (scalar transcendentals)
    vfloat2 qt = { sqrtf(-2.0f * __logf(pmA)), sqrtf(-2.0f * __logf(pmB)) };
    // central arg: r = (p-0.5)^2
    vfloat2 qc = { pa - 0.5f, pb - 0.5f };
    vfloat2 r  = qc * qc;

    // ---- tail polys (packed)
    vfloat2 numT = { -0.007784894002430293f, -0.007784894002430293f };
    numT = __builtin_elementwise_fma(numT, qt, (vfloat2)(-0.3223964580411365f));
    numT = __builtin_elementwise_fma(numT, qt, (vfloat2)(-2.400758277161838f));
    numT = __builtin_elementwise_fma(numT, qt, (vfloat2)(-2.549732539343734f));
    numT = __builtin_elementwise_fma(numT, qt, (vfloat2)( 4.374664141464968f));
    numT = __builtin_elementwise_fma(numT, qt, (vfloat2)( 2.938163982698783f));
    vfloat2 denT = { 0.007784695709041462f, 0.007784695709041462f };
    denT = __builtin_elementwise_fma(denT, qt, (vfloat2)(0.3224671290700398f));
    denT = __builtin_elementwise_fma(denT, qt, (vfloat2)(2.445134137142996f));
    denT = __builtin_elementwise_fma(denT, qt, (vfloat2)(3.754408661907416f));
    denT = __builtin_elementwise_fma(denT, qt, (vfloat2)(1.0f));

    // ---- central polys (packed)
    vfloat2 numC = { -39.69683028665376f, -39.69683028665376f };
    numC = __builtin_elementwise_fma(numC, r, (vfloat2)( 220.9460984245205f));
    numC = __builtin_elementwise_fma(numC, r, (vfloat2)(-275.9285104469687f));
    numC = __builtin_elementwise_fma(numC, r, (vfloat2)( 138.3577518672690f));
    numC = __builtin_elementwise_fma(numC, r, (vfloat2)( -30.66479806614716f));
    numC = __builtin_elementwise_fma(numC, r, (vfloat2)(   2.506628277459239f));
    vfloat2 denC = { -54.47609879822406f, -54.47609879822406f };
    denC = __builtin_elementwise_fma(denC, r, (vfloat2)( 161.5858368580409f));
    denC = __builtin_elementwise_fma(denC, r, (vfloat2)(-155.6989798598866f));
    denC = __builtin_elementwise_fma(denC, r, (vfloat2)(  66.80131188771972f));
    denC = __builtin_elementwise_fma(denC, r, (vfloat2)( -13.28068155288572f));
    denC = __builtin_elementwise_fma(denC, r, (vfloat2)(   1.0f));

    // ---- scalar select + one rcp per element
    float numA = tailA ? numT.x : numC.x;
    float denA = tailA ? denT.x : denC.x;
    float sA   = tailA ? (upA ? -1.0f : 1.0f) : qc.x;
    float numB = tailB ? numT.y : numC.y;
    float denB = tailB ? denT.y : denC.y;
    float sB   = tailB ? (upB ? -1.0f : 1.0f) : qc.y;

    vfloat2 out;
    out.x = sA * numA * __builtin_amdgcn_rcpf(denA);
    out.y = sB * numB * __builtin_amdgcn_rcpf(denB);
    return out;
}

__device__ __forceinline__ void set_label_bit(int c, unsigned& m0, unsigned& m1,
                                              unsigned& m2, unsigned& m3) {
    unsigned bit = 1u << (c & 31);
    int w = (c >> 5) & 3;
    if      (w == 0) m0 |= bit;
    else if (w == 1) m1 |= bit;
    else if (w == 2) m2 |= bit;
    else             m3 |= bit;
}

// ---------------------------------------------------------------------------
// Pass 1: presence bitmap only. 4 labels per thread (int4 loads).
__global__ void __launch_bounds__(256) bitmap_kernel(
    const int* __restrict__ C,
    unsigned* __restrict__ mask,
    int n)
{
    __shared__ unsigned sm[4];
    if (threadIdx.x < 4) sm[threadIdx.x] = 0u;
    __syncthreads();

    int i = blockIdx.x * blockDim.x + threadIdx.x;
    int base = i << 2;
    unsigned m0 = 0, m1 = 0, m2 = 0, m3 = 0;

    if (base + 3 < n) {
        int4 c = *reinterpret_cast<const int4*>(C + base);
        set_label_bit(c.x, m0, m1, m2, m3);
        set_label_bit(c.y, m0, m1, m2, m3);
        set_label_bit(c.z, m0, m1, m2, m3);
        set_label_bit(c.w, m0, m1, m2, m3);
    } else {
        for (int j = base; j < n && j < base + 4; ++j)
            set_label_bit(C[j], m0, m1, m2, m3);
    }

    #pragma unroll
    for (int off = 32; off > 0; off >>= 1) {
        m0 |= __shfl_down(m0, off, 64);
        m1 |= __shfl_down(m1, off, 64);
        m2 |= __shfl_down(m2, off, 64);
        m3 |= __shfl_down(m3, off, 64);
    }
    if ((threadIdx.x & 63) == 0) {
        if (m0) atomicOr(&sm[0], m0);
        if (m1) atomicOr(&sm[1], m1);
        if (m2) atomicOr(&sm[2], m2);
        if (m3) atomicOr(&sm[3], m3);
    }
    __syncthreads();
    if (threadIdx.x < 4) {
        unsigned v = sm[threadIdx.x];
        if (v) atomicOr(&mask[threadIdx.x], v);
    }
}

// ---------------------------------------------------------------------------
// Pass 2: one thread per float4 (4 consecutive k of one row).
// u and Phi(u) recomputed per thread (bit-identical; verified neutral R3).
__global__ void __launch_bounds__(256) map_kernel(
    const int* __restrict__ C,
    const float* __restrict__ eps,
    const float* __restrict__ mu_p,
    const float* __restrict__ sigma_p,
    const float4* __restrict__ U4,
    const uint4* __restrict__ mask4,
    float4* __restrict__ out4,
    int total4)
{
    int idx = blockIdx.x * blockDim.x + threadIdx.x;
    if (idx >= total4) return;
    int row = idx >> 5;        // K/4 = 32 float4 per row
    int k0  = (idx & 31) << 2;

    float4 Uv = U4[idx];       // plain coalesced load (NT load cost ~9us, R5)
    float  e  = eps[row];      // 32 threads share each value -> L1 broadcast
    int    c  = C[row];
    uint4  w  = *mask4;        // same 16B for all threads -> broadcast

    const float sg = sigma_p[0];   // uniform address -> scalar load
    const float mu = mu_p[0];
    float u   = fmaf(sg, e, mu);
    float phi = 0.5f * erfcf(-u * 0.7071067811865476f);

    // rank = popcount of presence bits strictly below c
    int cw = c >> 5;
    unsigned below = (1u << (c & 31)) - 1u;
    int rank = __popc(w.x & ((0 < cw) ? 0xFFFFFFFFu : ((0 == cw) ? below : 0u)))
             + __popc(w.y & ((1 < cw) ? 0xFFFFFFFFu : ((1 == cw) ? below : 0u)))
             + __popc(w.z & ((2 < cw) ? 0xFFFFFFFFu : ((2 == cw) ? below : 0u)))
             + __popc(w.w & ((3 < cw) ? 0xFFFFFFFFu : ((3 == cw) ? below : 0u)));

    const float lo = 1e-7f;
    const float hi = 0.99999988079071045f;  // fp32(1 - 1e-7), matches jnp.clip

    // clamp via v_med3_f32 (single instruction)
    float p0 = __builtin_amdgcn_fmed3f(Uv.x, lo, hi) * phi;
    float p1 = __builtin_amdgcn_fmed3f(Uv.y, lo, hi) * phi;
    float p2 = __builtin_amdgcn_fmed3f(Uv.z, lo, hi) * phi;
    float p3 = __builtin_amdgcn_fmed3f(Uv.w, lo, hi) * phi;

    vfloat2 z01 = ndtri2_fast(p0, p1);   // packed poly chains
    vfloat2 z23 = ndtri2_fast(p2, p3);

    vfloat4 o;
    o.x = (k0 + 0 == rank) ? u : z01.x;
    o.y = (k0 + 1 == rank) ? u : z01.y;
    o.z = (k0 + 2 == rank) ? u : z23.x;
    o.w = (k0 + 3 == rank) ? u : z23.y;

    // out is never re-read: stream it past the caches (full-line coalesced)
    __builtin_nontemporal_store(o, reinterpret_cast<vfloat4*>(&out4[idx]));
}

extern "C" void kernel_launch(void* const* d_in, const int* in_sizes, int n_in,
                              void* d_out, int out_size, void* d_ws, size_t ws_size,
                              hipStream_t stream) {
    const int*   C     = (const int*)d_in[0];
    const float* eps   = (const float*)d_in[1];
    const float4* U4   = (const float4*)d_in[2];
    const float* mu    = (const float*)d_in[3];
    const float* sigma = (const float*)d_in[4];
    float4* out4 = (float4*)d_out;

    unsigned* mask = (unsigned*)d_ws;

    int n = in_sizes[0];           // B*N = 262144 rows
    int total4 = out_size / 4;     // float4 count (unchanged from verified baseline)

    // ws is re-poisoned to 0xAA before every timed launch — zero the bitmap.
    (void)hipMemsetAsync(d_ws, 0, 4 * sizeof(unsigned), stream);

    int n4 = (n + 3) >> 2;
    int bb = (n4 + 255) / 256;
    bitmap_kernel<<<bb, 256, 0, stream>>>(C, mask, n);

    int mb = (total4 + 255) / 256;
    map_kernel<<<mb, 256, 0, stream>>>(C, eps, mu, sigma, U4,
                                       (const uint4*)mask, out4, total4);
}